// Round 7
// baseline (229.541 us; speedup 1.0000x reference)
//
#include <hip/hip_runtime.h>
#include <hip/hip_bf16.h>

#define N_NODES 40000
#define N_EDGES 640000
#define DIM     128
#define NB      157    // node blocks (256 threads)
#define GEMMB   625    // gemm blocks (64 rows each)
#define HEB     1250   // hist/scatter blocks (2 edges/thread)

typedef __attribute__((ext_vector_type(8))) short short8;
typedef __attribute__((ext_vector_type(4))) float f32x4;

__device__ inline short f2bf(float f) {
    __hip_bfloat16 h = __float2bfloat16(f);
    return *reinterpret_cast<short*>(&h);
}
__device__ inline float bf2f(short u) {
    union { unsigned int i; float f; } x;
    x.i = ((unsigned int)(unsigned short)u) << 16;
    return x.f;
}

// fragment-order index for element (k,n) of a 128x128 W, matching the
// MFMA B-fragment read: lane l reads slot (kb*8+nt)*64 + l as short8.
__device__ inline int fragidx(int k, int n) {
    int kb = k >> 5, kq = (k >> 3) & 3, j = k & 7;
    int nt = n >> 4, nl = n & 15;
    return (((kb * 8 + nt) * 64 + kq * 16 + nl) * 8 + j);
}

// ---------------------------------------------------------------------------
// Dispatch 2: blocks [0,HEB) = edge histogram; [HEB,HEB+64) = weight prep.
// ---------------------------------------------------------------------------
__global__ __launch_bounds__(256) void hist_prep(const int* __restrict__ rows,
                                                 int* __restrict__ counts,
                                                 const float* __restrict__ Wt,
                                                 const float* __restrict__ W0,
                                                 const float* __restrict__ W1,
                                                 const float* __restrict__ bt,
                                                 short* __restrict__ WtF,
                                                 short* __restrict__ WfF,
                                                 short* __restrict__ W1F,
                                                 float* __restrict__ btf) {
    int b = blockIdx.x;
    if (b < HEB) {
        int gid = b * 256 + threadIdx.x;            // 0..319999
        atomicAdd(&counts[rows[gid]], 1);
        atomicAdd(&counts[rows[gid + HEB * 256]], 1);
    } else {
        int gid = (b - HEB) * 256 + threadIdx.x;    // 0..16383
        int k = gid >> 7, n = gid & 127;
        float wf = 0.f;
        for (int kk = 0; kk < 128; ++kk)
            wf += Wt[k * 128 + kk] * W0[kk * 128 + n];
        int fi = fragidx(k, n);
        WtF[fi] = f2bf(Wt[k * 128 + n]);
        W1F[fi] = f2bf(W1[k * 128 + n]);
        WfF[fi] = f2bf(wf);
        if (gid < 128) {
            float s = 0.f;
            for (int kk = 0; kk < 128; ++kk) s += bt[kk] * W0[kk * 128 + n];
            btf[n] = s;
        }
    }
}

// ---------------------------------------------------------------------------
// scan pass 1: per-block exclusive scan of counts + block totals
// ---------------------------------------------------------------------------
__global__ __launch_bounds__(256) void scan_local(const int* __restrict__ counts,
                                                  int* __restrict__ excl,
                                                  int* __restrict__ blkTot) {
    __shared__ int sh[256];
    const int t = threadIdx.x;
    int i = blockIdx.x * 256 + t;
    int c = (i < N_NODES) ? counts[i] : 0;
    int val = c;
    sh[t] = val;
    __syncthreads();
    for (int off = 1; off < 256; off <<= 1) {
        int a = (t >= off) ? sh[t - off] : 0;
        __syncthreads();
        val += a;
        sh[t] = val;
        __syncthreads();
    }
    if (i < N_NODES) excl[i] = val - c;
    if (t == 255) blkTot[blockIdx.x] = val;
}

// ---------------------------------------------------------------------------
// scan pass 2: every block redundantly scans the NB block totals in LDS,
// picks its own offset, finalizes cursor/row_ptr.
// ---------------------------------------------------------------------------
__global__ __launch_bounds__(256) void scan_final(const int* __restrict__ excl,
                                                  const int* __restrict__ blkTot,
                                                  int* __restrict__ cursor,
                                                  int* __restrict__ row_ptr) {
    __shared__ int sh[256];
    const int t = threadIdx.x;
    int v = (t < NB) ? blkTot[t] : 0;
    int val = v;
    sh[t] = val;
    __syncthreads();
    for (int off = 1; off < 256; off <<= 1) {
        int a = (t >= off) ? sh[t - off] : 0;
        __syncthreads();
        val += a;
        sh[t] = val;
        __syncthreads();
    }
    int blkOff = (blockIdx.x == 0) ? 0 : sh[blockIdx.x - 1];
    int i = blockIdx.x * 256 + t;
    if (i < N_NODES) {
        int u = excl[i] + blkOff;
        cursor[i]  = u;
        row_ptr[i] = u;
    }
    if (i == 0) row_ptr[N_NODES] = N_EDGES;
}

// ---------------------------------------------------------------------------
// Dispatch 5: blocks [0,GEMMB) = dual GEMM over x:
//   H = x@Wt + bt (fp32, d_out), Z0 = bf16(x@(Wt@W0) + bt@W0)
// blocks [GEMMB, GEMMB+HEB) = scatter (bucket edges by dest, u16 adj).
// ---------------------------------------------------------------------------
__global__ __launch_bounds__(256) void dualgemm_scatter(const float* __restrict__ A,
                                                        const short* __restrict__ WtF,
                                                        const short* __restrict__ WfF,
                                                        const float* __restrict__ bt,
                                                        const float* __restrict__ btf,
                                                        float* __restrict__ H,
                                                        __hip_bfloat16* __restrict__ Z,
                                                        const int* __restrict__ rows,
                                                        const int* __restrict__ cols,
                                                        int* __restrict__ cursor,
                                                        unsigned short* __restrict__ adj) {
    if (blockIdx.x >= GEMMB) {
        int gid = (blockIdx.x - GEMMB) * 256 + threadIdx.x;   // 0..319999
#pragma unroll
        for (int h = 0; h < 2; ++h) {
            int e   = gid + h * HEB * 256;
            int r   = rows[e];
            int pos = atomicAdd(&cursor[r], 1);
            adj[pos] = (unsigned short)cols[e];
        }
        return;
    }

    const int t    = threadIdx.x;
    const int wave = t >> 6;
    const int l    = t & 63;
    const int nl   = l & 15;
    const int quad = l >> 4;
    const int wRow = blockIdx.x * 64 + wave * 16;

    f32x4 accH[8], accZ[8];
#pragma unroll
    for (int nt = 0; nt < 8; ++nt) {
        accH[nt] = (f32x4){0.f, 0.f, 0.f, 0.f};
        accZ[nt] = (f32x4){0.f, 0.f, 0.f, 0.f};
    }

#pragma unroll
    for (int kb = 0; kb < 4; ++kb) {
        const float* ap = A + (size_t)(wRow + nl) * 128 + kb * 32 + quad * 8;
        float4 f0 = *(const float4*)ap;
        float4 f1 = *(const float4*)(ap + 4);
        short8 afrag;
        afrag[0] = f2bf(f0.x); afrag[1] = f2bf(f0.y);
        afrag[2] = f2bf(f0.z); afrag[3] = f2bf(f0.w);
        afrag[4] = f2bf(f1.x); afrag[5] = f2bf(f1.y);
        afrag[6] = f2bf(f1.z); afrag[7] = f2bf(f1.w);
#pragma unroll
        for (int nt = 0; nt < 8; ++nt) {
            int off = ((kb * 8 + nt) * 64 + l) * 8;
            short8 bt_frag = *(const short8*)&WtF[off];
            short8 bf_frag = *(const short8*)&WfF[off];
            accH[nt] = __builtin_amdgcn_mfma_f32_16x16x32_bf16(afrag, bt_frag, accH[nt], 0, 0, 0);
            accZ[nt] = __builtin_amdgcn_mfma_f32_16x16x32_bf16(afrag, bf_frag, accZ[nt], 0, 0, 0);
        }
    }

#pragma unroll
    for (int nt = 0; nt < 8; ++nt) {
        int col = nt * 16 + nl;
        float bH = bt[col];
        float bZ = btf[col];
#pragma unroll
        for (int r = 0; r < 4; ++r) {
            int row = wRow + quad * 4 + r;
            H[(size_t)row * 128 + col] = accH[nt][r] + bH;
            *(short*)&Z[(size_t)row * 128 + col] = f2bf(accZ[nt][r] + bZ);
        }
    }
}

// ---------------------------------------------------------------------------
// Dispatch 6: fused layer-0 agg + layer-1 GEMM.
// 16 nodes/block. Phase 1: wave w gathers nodes w*4+u from Z0, computes
// hnew = H[node] + relu(agg+b0) (fp32), writes H in place (own rows only),
// stages bf16(hnew) in padded LDS. Phase 2: Z1[16x128] = hs @ W1 -> Z1
// buffer (DISTINCT from Z0 — no aliasing with concurrent gatherers).
// ---------------------------------------------------------------------------
__global__ __launch_bounds__(256) void agg0_gemm(const __hip_bfloat16* __restrict__ z0,
                                                 const int* __restrict__ row_ptr,
                                                 const unsigned short* __restrict__ adj,
                                                 const float* __restrict__ bias,
                                                 const short* __restrict__ W1F,
                                                 float* __restrict__ H,
                                                 __hip_bfloat16* __restrict__ Z1) {
    __shared__ short hs[16][136];   // +8 shorts pad

    const int t    = threadIdx.x;
    const int wave = t >> 6;
    const int l    = t & 63;
    const int quad = l >> 4;
    const int sl   = l & 15;
    const int nodeBase = blockIdx.x * 16;

#pragma unroll
    for (int u = 0; u < 4; ++u) {
        const int m    = wave * 4 + u;
        const int node = nodeBase + m;
        const int s = row_ptr[node];
        const int e = row_ptr[node + 1];

        float acc[8];
#pragma unroll
        for (int j = 0; j < 8; ++j) acc[j] = 0.f;

        int it = s + quad;
        for (; it + 12 < e; it += 16) {
            int c0 = adj[it];
            int c1 = adj[it + 4];
            int c2 = adj[it + 8];
            int c3 = adj[it + 12];
            short8 v0 = *(const short8*)&z0[(size_t)c0 * DIM + sl * 8];
            short8 v1 = *(const short8*)&z0[(size_t)c1 * DIM + sl * 8];
            short8 v2 = *(const short8*)&z0[(size_t)c2 * DIM + sl * 8];
            short8 v3 = *(const short8*)&z0[(size_t)c3 * DIM + sl * 8];
#pragma unroll
            for (int j = 0; j < 8; ++j)
                acc[j] += (bf2f(v0[j]) + bf2f(v1[j])) + (bf2f(v2[j]) + bf2f(v3[j]));
        }
        for (; it + 4 < e; it += 8) {
            int c0 = adj[it];
            int c1 = adj[it + 4];
            short8 v0 = *(const short8*)&z0[(size_t)c0 * DIM + sl * 8];
            short8 v1 = *(const short8*)&z0[(size_t)c1 * DIM + sl * 8];
#pragma unroll
            for (int j = 0; j < 8; ++j) acc[j] += bf2f(v0[j]) + bf2f(v1[j]);
        }
        if (it < e) {
            int c = adj[it];
            short8 v = *(const short8*)&z0[(size_t)c * DIM + sl * 8];
#pragma unroll
            for (int j = 0; j < 8; ++j) acc[j] += bf2f(v[j]);
        }

#pragma unroll
        for (int j = 0; j < 8; ++j) acc[j] += __shfl_xor(acc[j], 16, 64);
#pragma unroll
        for (int j = 0; j < 8; ++j) acc[j] += __shfl_xor(acc[j], 32, 64);

        if (quad == 0) {
            float* hp = H + (size_t)node * DIM + sl * 8;
            float4 h0 = *(float4*)hp;
            float4 h1 = *(float4*)(hp + 4);
            float4 b0v = *(const float4*)&bias[sl * 8];
            float4 b1v = *(const float4*)&bias[sl * 8 + 4];
            float r[8];
            r[0] = acc[0] + b0v.x; r[1] = acc[1] + b0v.y; r[2] = acc[2] + b0v.z; r[3] = acc[3] + b0v.w;
            r[4] = acc[4] + b1v.x; r[5] = acc[5] + b1v.y; r[6] = acc[6] + b1v.z; r[7] = acc[7] + b1v.w;
            float hn[8];
            hn[0] = h0.x; hn[1] = h0.y; hn[2] = h0.z; hn[3] = h0.w;
            hn[4] = h1.x; hn[5] = h1.y; hn[6] = h1.z; hn[7] = h1.w;
            short8 o;
#pragma unroll
            for (int j = 0; j < 8; ++j) {
                float rr = r[j] > 0.f ? r[j] : 0.f;
                hn[j] += rr;
                o[j] = f2bf(hn[j]);
            }
            *(float4*)hp       = make_float4(hn[0], hn[1], hn[2], hn[3]);
            *(float4*)(hp + 4) = make_float4(hn[4], hn[5], hn[6], hn[7]);
            *(short8*)&hs[m][sl * 8] = o;
        }
    }
    __syncthreads();

    // phase 2: Z1[16x128] = hs @ W1 ; wave handles cols [wave*32, wave*32+32)
    f32x4 acc2[2];
    acc2[0] = (f32x4){0.f, 0.f, 0.f, 0.f};
    acc2[1] = (f32x4){0.f, 0.f, 0.f, 0.f};
#pragma unroll
    for (int kb = 0; kb < 4; ++kb) {
        short8 afrag = *(const short8*)&hs[sl][kb * 32 + quad * 8];
#pragma unroll
        for (int nt2 = 0; nt2 < 2; ++nt2) {
            int nt = wave * 2 + nt2;
            short8 bfrag = *(const short8*)&W1F[((kb * 8 + nt) * 64 + l) * 8];
            acc2[nt2] = __builtin_amdgcn_mfma_f32_16x16x32_bf16(afrag, bfrag, acc2[nt2], 0, 0, 0);
        }
    }
#pragma unroll
    for (int nt2 = 0; nt2 < 2; ++nt2) {
        int col = (wave * 2 + nt2) * 16 + sl;
#pragma unroll
        for (int r = 0; r < 4; ++r) {
            int row = nodeBase + quad * 4 + r;
            *(short*)&Z1[(size_t)row * 128 + col] = f2bf(acc2[nt2][r]);
        }
    }
}

// ---------------------------------------------------------------------------
// Final aggregation: one wave per node; H[node] += relu(agg(Z1)+b1).
// Reads/writes only its own H row (fp32 in d_out) — race-free.
// ---------------------------------------------------------------------------
__global__ __launch_bounds__(256) void agg_final(const __hip_bfloat16* __restrict__ z,
                                                 const int* __restrict__ row_ptr,
                                                 const unsigned short* __restrict__ adj,
                                                 const float* __restrict__ bias,
                                                 float* __restrict__ H) {
    const int wave = threadIdx.x >> 6;
    const int l    = threadIdx.x & 63;
    const int quad = l >> 4;
    const int sl   = l & 15;
    const int node = blockIdx.x * 4 + wave;
    if (node >= N_NODES) return;

    const int s = row_ptr[node];
    const int e = row_ptr[node + 1];

    float acc[8];
#pragma unroll
    for (int j = 0; j < 8; ++j) acc[j] = 0.f;

    int it = s + quad;
    for (; it + 12 < e; it += 16) {
        int c0 = adj[it];
        int c1 = adj[it + 4];
        int c2 = adj[it + 8];
        int c3 = adj[it + 12];
        short8 v0 = *(const short8*)&z[(size_t)c0 * DIM + sl * 8];
        short8 v1 = *(const short8*)&z[(size_t)c1 * DIM + sl * 8];
        short8 v2 = *(const short8*)&z[(size_t)c2 * DIM + sl * 8];
        short8 v3 = *(const short8*)&z[(size_t)c3 * DIM + sl * 8];
#pragma unroll
        for (int j = 0; j < 8; ++j)
            acc[j] += (bf2f(v0[j]) + bf2f(v1[j])) + (bf2f(v2[j]) + bf2f(v3[j]));
    }
    for (; it + 4 < e; it += 8) {
        int c0 = adj[it];
        int c1 = adj[it + 4];
        short8 v0 = *(const short8*)&z[(size_t)c0 * DIM + sl * 8];
        short8 v1 = *(const short8*)&z[(size_t)c1 * DIM + sl * 8];
#pragma unroll
        for (int j = 0; j < 8; ++j) acc[j] += bf2f(v0[j]) + bf2f(v1[j]);
    }
    if (it < e) {
        int c = adj[it];
        short8 v = *(const short8*)&z[(size_t)c * DIM + sl * 8];
#pragma unroll
        for (int j = 0; j < 8; ++j) acc[j] += bf2f(v[j]);
    }

#pragma unroll
    for (int j = 0; j < 8; ++j) acc[j] += __shfl_xor(acc[j], 16, 64);
#pragma unroll
    for (int j = 0; j < 8; ++j) acc[j] += __shfl_xor(acc[j], 32, 64);

    if (quad == 0) {
        float* hp = H + (size_t)node * DIM + sl * 8;
        float4 h0 = *(float4*)hp;
        float4 h1 = *(float4*)(hp + 4);
        float4 b0 = *(const float4*)&bias[sl * 8];
        float4 b1 = *(const float4*)&bias[sl * 8 + 4];
        float r0 = acc[0] + b0.x, r1 = acc[1] + b0.y, r2 = acc[2] + b0.z, r3 = acc[3] + b0.w;
        float r4 = acc[4] + b1.x, r5 = acc[5] + b1.y, r6 = acc[6] + b1.z, r7 = acc[7] + b1.w;
        h0.x += r0 > 0.f ? r0 : 0.f;  h0.y += r1 > 0.f ? r1 : 0.f;
        h0.z += r2 > 0.f ? r2 : 0.f;  h0.w += r3 > 0.f ? r3 : 0.f;
        h1.x += r4 > 0.f ? r4 : 0.f;  h1.y += r5 > 0.f ? r5 : 0.f;
        h1.z += r6 > 0.f ? r6 : 0.f;  h1.w += r7 > 0.f ? r7 : 0.f;
        *(float4*)hp       = h0;
        *(float4*)(hp + 4) = h1;
    }
}

// ---------------------------------------------------------------------------
extern "C" void kernel_launch(void* const* d_in, const int* in_sizes, int n_in,
                              void* d_out, int out_size, void* d_ws, size_t ws_size,
                              hipStream_t stream) {
    const float* x   = (const float*)d_in[0];
    const int*   ei  = (const int*)d_in[1];
    const float* W_t = (const float*)d_in[2];
    const float* b_t = (const float*)d_in[3];
    const float* W0  = (const float*)d_in[4];
    const float* b0  = (const float*)d_in[5];
    const float* W1  = (const float*)d_in[6];
    const float* b1  = (const float*)d_in[7];

    const int* rows = ei;
    const int* cols = ei + N_EDGES;

    float* H = (float*)d_out;   // fp32 h lives here the whole time

    // workspace layout (~22.6 MB)
    char* w = (char*)d_ws;
    __hip_bfloat16* Z0 = (__hip_bfloat16*)w;  w += (size_t)N_NODES * DIM * 2;
    __hip_bfloat16* Z1 = (__hip_bfloat16*)w;  w += (size_t)N_NODES * DIM * 2;
    short* WtF = (short*)w;  w += 128 * 128 * 2;
    short* WfF = (short*)w;  w += 128 * 128 * 2;
    short* W1F = (short*)w;  w += 128 * 128 * 2;
    float* btf = (float*)w;  w += 128 * 4;
    int* row_ptr = (int*)w;  w += (N_NODES + 1) * 4;
    int* cursor  = (int*)w;  w += N_NODES * 4;
    int* counts  = (int*)w;  w += N_NODES * 4;
    int* excl    = (int*)w;  w += N_NODES * 4;
    int* blkTot  = (int*)w;  w += 256 * 4;
    unsigned short* adj = (unsigned short*)w;   // E u16

    const int aggBlocks = (N_NODES + 3) / 4;

    // 1: zero counts
    hipMemsetAsync(counts, 0, N_NODES * sizeof(int), stream);

    // 2: edge histogram | weight prep
    hist_prep<<<HEB + 64, 256, 0, stream>>>(rows, counts, W_t, W0, W1, b_t,
                                            WtF, WfF, W1F, btf);

    // 3-4: two-level scan -> row_ptr / cursor
    scan_local<<<NB, 256, 0, stream>>>(counts, excl, blkTot);
    scan_final<<<NB, 256, 0, stream>>>(excl, blkTot, cursor, row_ptr);

    // 5: dual GEMM over x | scatter edges into CSR (overlapped)
    dualgemm_scatter<<<GEMMB + HEB, 256, 0, stream>>>(x, WtF, WfF, b_t, btf, H, Z0,
                                                      rows, cols, cursor, adj);

    // 6: layer-0 agg + layer-1 GEMM fused: H += relu(agg(Z0)+b0); Z1 = bf16(H)@W1
    agg0_gemm<<<N_NODES / 16, 256, 0, stream>>>(Z0, row_ptr, adj, b0, W1F, H, Z1);

    // 7: final agg: H += relu(agg(Z1) + b1)
    agg_final<<<aggBlocks, 256, 0, stream>>>(Z1, row_ptr, adj, b1, H);
}